// Round 11
// baseline (72.887 us; speedup 1.0000x reference)
//
#include <hip/hip_runtime.h>

#define L_COLS 2048
#define NSLOT 64

typedef float vf4 __attribute__((ext_vector_type(4)));

__device__ __forceinline__ float wave_red(float v) {
#pragma unroll
    for (int m = 32; m >= 1; m >>= 1) v += __shfl_xor(v, m, 64);
    return v;
}

// ---------------------------------------------------------------------------
// Init: one wave computes slice bounds from ppm and zeroes the 64 acc slots.
// Python: start = min(where(ppm <= hi)), stop = max(where(ppm >= lo)); [start:stop)
// windows: gaba(2.8,3.2), glx_shape(3.6,3.9), glx_range(3.55,3.95)
// ---------------------------------------------------------------------------
__global__ __launch_bounds__(64) void init_kernel(const float* __restrict__ ppm,
                                                  float* __restrict__ acc,
                                                  int* __restrict__ ob) {
    const int lane = threadIdx.x;
    ((vf4*)acc)[lane] = (vf4){0.f, 0.f, 0.f, 0.f};   // 64 slots x 4 floats

    int mn0 = 0x7fffffff, mn1 = 0x7fffffff, mn2 = 0x7fffffff;
    int mx0 = -1, mx1 = -1, mx2 = -1;
    const vf4* __restrict__ p4 = (const vf4*)ppm;
#pragma unroll
    for (int k = 0; k < L_COLS / 256; ++k) {
        const int j = k * 64 + lane;
        const vf4 pv = p4[j];
        const float ps[4] = {pv.x, pv.y, pv.z, pv.w};
#pragma unroll
        for (int e = 0; e < 4; ++e) {
            const int c = 4 * j + e;
            const float p = ps[e];
            if (p <= 3.2f)  mn0 = min(mn0, c);
            if (p >= 2.8f)  mx0 = max(mx0, c);
            if (p <= 3.9f)  mn1 = min(mn1, c);
            if (p >= 3.6f)  mx1 = max(mx1, c);
            if (p <= 3.95f) mn2 = min(mn2, c);
            if (p >= 3.55f) mx2 = max(mx2, c);
        }
    }
#pragma unroll
    for (int m = 32; m >= 1; m >>= 1) {
        mn0 = min(mn0, __shfl_xor(mn0, m, 64));
        mx0 = max(mx0, __shfl_xor(mx0, m, 64));
        mn1 = min(mn1, __shfl_xor(mn1, m, 64));
        mx1 = max(mx1, __shfl_xor(mx1, m, 64));
        mn2 = min(mn2, __shfl_xor(mn2, m, 64));
        mx2 = max(mx2, __shfl_xor(mx2, m, 64));
    }
    if (lane == 0) {
        ob[0] = mn0; ob[1] = mx0;   // gaba  [lo:hi)
        ob[2] = mn1; ob[3] = mx1;   // glx shape
        ob[4] = mn2; ob[5] = mx2;   // glx range
    }
}

// ---------------------------------------------------------------------------
// One BLOCK per row, 256 threads. Each thread: 4 independent coalesced
// dwordx4 loads (cols 4t..4t+3 and 1024+4t..+3) -> no serial load chain;
// MLP comes from thread count (8 resident blocks/CU x 16KB in flight).
// Pearson via raw moments (norm01 is positive-affine -> invariant).
// Block partials -> acc slot (blockIdx & 63): [score, gaba_mae, glx_mae, gl]
// ---------------------------------------------------------------------------
__global__ __launch_bounds__(256) void loss_main(const float* __restrict__ x,
                                                 const float* __restrict__ y,
                                                 const int* __restrict__ ob,
                                                 float* __restrict__ acc) {
    const int t    = threadIdx.x;
    const int lane = t & 63;
    const int wv   = t >> 6;
    const long row = blockIdx.x;

    const int g_lo = ob[0], g_hi = ob[1];
    const int s_lo = ob[2], s_hi = ob[3];
    const int r_lo = ob[4], r_hi = ob[5];

    const vf4* __restrict__ x4 = (const vf4*)(x + row * L_COLS);
    const vf4* __restrict__ y4 = (const vf4*)(y + row * L_COLS);

    // 4 independent loads, all issued before any use
    const vf4 xa = x4[t];
    const vf4 xb = x4[256 + t];
    const vf4 ya = y4[t];
    const vf4 yb = y4[256 + t];

    float gl = 0.f;
    float a_sx = 0, a_sy = 0, a_xy = 0, a_xx = 0, a_yy = 0, a_mae = 0;
    float b_sx = 0, b_sy = 0, b_xy = 0, b_xx = 0, b_yy = 0;
    float r_mae = 0;

#pragma unroll
    for (int h = 0; h < 2; ++h) {
        const vf4 xv = h ? xb : xa;
        const vf4 yv = h ? yb : ya;
        const int c0 = h * 1024 + 4 * t;
        const float xs[4] = {xv.x, xv.y, xv.z, xv.w};
        const float ys[4] = {yv.x, yv.y, yv.z, yv.w};
#pragma unroll
        for (int e = 0; e < 4; ++e) {
            const int c = c0 + e;
            const float xe = xs[e], ye = ys[e];
            const float d = fabsf(xe - ye);
            gl += d;
            if (c >= g_lo && c < g_hi) {
                a_sx += xe; a_sy += ye; a_xy += xe * ye;
                a_xx += xe * xe; a_yy += ye * ye; a_mae += d;
            }
            if (c >= s_lo && c < s_hi) {
                b_sx += xe; b_sy += ye; b_xy += xe * ye;
                b_xx += xe * xe; b_yy += ye * ye;
            }
            if (c >= r_lo && c < r_hi) r_mae += d;
        }
    }

    // 13 wave reductions -> per-wave partials
    float v0  = wave_red(gl);
    float v1  = wave_red(a_sx), v2 = wave_red(a_sy), v3 = wave_red(a_xy);
    float v4  = wave_red(a_xx), v5 = wave_red(a_yy), v6 = wave_red(a_mae);
    float v7  = wave_red(b_sx), v8 = wave_red(b_sy), v9 = wave_red(b_xy);
    float v10 = wave_red(b_xx), v11 = wave_red(b_yy);
    float v12 = wave_red(r_mae);

    __shared__ float part[4][13];
    if (lane == 0) {
        part[wv][0] = v0;  part[wv][1] = v1;  part[wv][2] = v2;
        part[wv][3] = v3;  part[wv][4] = v4;  part[wv][5] = v5;
        part[wv][6] = v6;  part[wv][7] = v7;  part[wv][8] = v8;
        part[wv][9] = v9;  part[wv][10] = v10; part[wv][11] = v11;
        part[wv][12] = v12;
    }
    __syncthreads();
    if (t == 0) {
        float s[13];
#pragma unroll
        for (int i = 0; i < 13; ++i)
            s[i] = (part[0][i] + part[1][i]) + (part[2][i] + part[3][i]);
        const float ng = (float)(g_hi - g_lo);
        const float ns = (float)(s_hi - s_lo);
        const float covA = s[3] - s[1] * s[2] / ng;
        const float vAx  = s[4] - s[1] * s[1] / ng;
        const float vAy  = s[5] - s[2] * s[2] / ng;
        const float scoreA = covA * rsqrtf(vAx * vAy);
        const float covB = s[9] - s[7] * s[8] / ns;
        const float vBx  = s[10] - s[7] * s[7] / ns;
        const float vBy  = s[11] - s[8] * s[8] / ns;
        const float scoreB = covB * rsqrtf(vBx * vBy);
        float* slot = acc + 4 * (blockIdx.x & (NSLOT - 1));
        atomicAdd(&slot[0], 0.6f * scoreA + 0.4f * scoreB);
        atomicAdd(&slot[1], s[6]);    // gaba |d|
        atomicAdd(&slot[2], s[12]);   // glx range |d|
        atomicAdd(&slot[3], s[0]);    // global |d|
    }
}

// ---------------------------------------------------------------------------
// Finalize: one wave reduces the 64 slots and emits the scalar loss.
// ---------------------------------------------------------------------------
__global__ __launch_bounds__(64) void finalize_kernel(const float* __restrict__ acc,
                                                      const int* __restrict__ ob,
                                                      int Brows, float* __restrict__ out) {
    const int lane = threadIdx.x;
    vf4 v = ((const vf4*)acc)[lane];
    v.x = wave_red(v.x);
    v.y = wave_red(v.y);
    v.z = wave_red(v.z);
    v.w = wave_red(v.w);
    if (lane == 0) {
        const float ng = (float)(ob[1] - ob[0]);
        const float nr = (float)(ob[5] - ob[4]);
        const float Bf = (float)Brows;
        const float shape_loss = 1.f - v.x / Bf;
        const float gaba_mae = v.y / (Bf * ng);
        const float glx_mae  = v.z / (Bf * nr);
        const float glob_mae = v.w / (Bf * (float)L_COLS);
        const float range_loss = (gaba_mae * 6.f + glx_mae * 3.f + glob_mae) * 0.1f;
        out[0] = shape_loss + range_loss * 0.5f;
    }
}

extern "C" void kernel_launch(void* const* d_in, const int* in_sizes, int n_in,
                              void* d_out, int out_size, void* d_ws, size_t ws_size,
                              hipStream_t stream) {
    const float* x   = (const float*)d_in[0];
    const float* ppm = (const float*)d_in[1];
    const float* y   = (const float*)d_in[2];
    const int L = in_sizes[1];          // 2048 (== L_COLS)
    const int Brows = in_sizes[0] / L;  // 8192

    float* acc = (float*)d_ws;                    // 64 slots x 4 floats = 1 KB
    int*   ob  = (int*)((char*)d_ws + 1024);      // 6 ints of bounds

    init_kernel<<<1, 64, 0, stream>>>(ppm, acc, ob);
    loss_main<<<Brows, 256, 0, stream>>>(x, y, ob, acc);
    finalize_kernel<<<1, 64, 0, stream>>>(acc, ob, Brows, (float*)d_out);
}